// Round 2
// baseline (3249.636 us; speedup 1.0000x reference)
//
#include <hip/hip_runtime.h>
#include <math.h>

typedef float v2f __attribute__((ext_vector_type(2)));

// ---------------- problem constants ----------------
#define B_    32
#define CIN   128
#define CHID  256
#define H_    60
#define W_    80
#define COUT  65
#define HP    480
#define WP    640
#define TOPK  1000
#define CAND_MAX 8192
#define DET_THRESH 0.015f

// ---------------- output layout (floats) ----------------
#define LOGITS_N (B_*COUT*H_*W_)        // 9,984,000
#define PROB_N   (B_*HP*WP)             // 9,830,400
#define PROB_OFF (LOGITS_N)
#define NMS_OFF  (PROB_OFF + PROB_N)
#define PRED_OFF (NMS_OFF + PROB_N)

// ---------------- workspace layout (float offsets) ----------------
#define WT_N   (CHID*CIN*9)             // 294,912
#define WT_OFF 0
#define SA_OFF (WT_OFF + WT_N)
#define TA_OFF (SA_OFF + 256)
#define SB_OFF (TA_OFF + 256)
#define TB_OFF (SB_OFF + 128)
#define H_OFF  (TB_OFF + 128)
#define H_N    (B_*H_*W_*CHID)          // 39,321,600
#define CAND_OFF (H_OFF + H_N)
#define CNT_OFF  (CAND_OFF + B_*CAND_MAX)
#define KTH_OFF  (CNT_OFF + 32)
#define WT1_OFF  (KTH_OFF + 32)
#define WT1_N    (COUT*CHID)            // 16,640

// =====================================================================
// K0: weight transpose + BN folding (conv3 transposed wt, conv1 folded wt1)
// =====================================================================
__global__ void prep_kernel(const float* __restrict__ wa,
                            const float* __restrict__ ba, const float* __restrict__ ga,
                            const float* __restrict__ bta, const float* __restrict__ ma,
                            const float* __restrict__ va,
                            const float* __restrict__ wb, const float* __restrict__ bb,
                            const float* __restrict__ gb, const float* __restrict__ btb,
                            const float* __restrict__ mb, const float* __restrict__ vb,
                            float* __restrict__ wt,
                            float* __restrict__ sa, float* __restrict__ ta,
                            float* __restrict__ tb, float* __restrict__ wt1)
{
    int gid = blockIdx.x * 256 + threadIdx.x;
    if (gid < WT_N) {
        int oc = gid & 255;
        int rest = gid >> 8;          // [0,1152)
        int s = rest % 3;
        int r = (rest / 3) % 3;
        int ic = rest / 9;
        wt[gid] = wa[((oc * CIN + ic) * 3 + r) * 3 + s];
    } else if (gid < WT_N + 256) {
        int oc = gid - WT_N;
        float inv = ga[oc] / sqrtf(va[oc] + 1e-5f);
        sa[oc] = inv;
        ta[oc] = (ba[oc] - ma[oc]) * inv + bta[oc];
    } else if (gid < WT_N + 256 + COUT) {
        int oc = gid - (WT_N + 256);
        float inv = gb[oc] / sqrtf(vb[oc] + 1e-5f);
        tb[oc] = (bb[oc] - mb[oc]) * inv + btb[oc];
    } else if (gid < WT_N + 256 + COUT + WT1_N) {
        int i = gid - (WT_N + 256 + COUT);
        int oc = i >> 8;
        float inv = gb[oc] / sqrtf(vb[oc] + 1e-5f);
        wt1[i] = wb[i] * inv;        // fold BN scale into conv1 weights
    }
}

// =====================================================================
// conv3 shared staging macro (identical for both variants)
// =====================================================================
#define CONV3_PROLOGUE                                                          \
    __shared__ float xs[8][18][20];                                             \
    __shared__ float wsh[8][9][64];                                             \
    int bid = blockIdx.x;                                                       \
    int ct = bid % 5;                                                           \
    int rt = (bid / 5) & 3;                                                     \
    int ot = (bid / 20) & 3;                                                    \
    int b  = b0 + bid / 80;                                                     \
    int x0 = ct * 16, y0 = rt * 16, oc0 = ot * 64;                              \
    int t = threadIdx.x;                                                        \
    int toc = t & 7;                                                            \
    int g = t >> 3;                                                             \
    int trow = g & 15;                                                          \
    int c0 = (g >> 4) * 8;                                                      \
    const float* xb = x + (size_t)b * CIN * H_ * W_;

#define CONV3_STAGE(cc)                                                         \
    {                                                                           \
        int ic0 = (cc) * 8;                                                     \
        __syncthreads();                                                        \
        for (int idx = t; idx < 8 * 18 * 18; idx += 256) {                      \
            int c = idx % 18;                                                   \
            int rr = (idx / 18) % 18;                                           \
            int ic = idx / 324;                                                 \
            int gy = y0 - 1 + rr;                                               \
            int gx = x0 - 1 + c;                                                \
            float v = 0.f;                                                      \
            if (gy >= 0 && gy < H_ && gx >= 0 && gx < W_)                       \
                v = xb[(ic0 + ic) * (H_ * W_) + gy * W_ + gx];                  \
            xs[ic][rr][c] = v;                                                  \
        }                                                                       \
        for (int idx = t; idx < 8 * 9 * 64; idx += 256) {                       \
            int ol = idx & 63;                                                  \
            int q = idx >> 6;                                                   \
            int tap = q % 9;                                                    \
            int ic = q / 9;                                                     \
            wsh[ic][tap][ol] = wt[((ic0 + ic) * 9 + tap) * 256 + oc0 + ol];     \
        }                                                                       \
        __syncthreads();                                                        \
    }

// =====================================================================
// K1a: conv3x3 scalar f32 (round-1 baseline structure)
// =====================================================================
__global__ __launch_bounds__(256) void conv3_kernel(const float* __restrict__ x,
                                                    const float* __restrict__ wt,
                                                    const float* __restrict__ sa,
                                                    const float* __restrict__ ta,
                                                    float* __restrict__ h, int b0)
{
    CONV3_PROLOGUE

    float acc[8][8];
#pragma unroll
    for (int o = 0; o < 8; ++o)
#pragma unroll
        for (int p = 0; p < 8; ++p) acc[o][p] = 0.f;

    for (int cc = 0; cc < 16; ++cc) {
        CONV3_STAGE(cc)
#pragma unroll
        for (int ic = 0; ic < 8; ++ic) {
#pragma unroll
            for (int dy = 0; dy < 3; ++dy) {
                float4 xa = *(const float4*)&xs[ic][trow + dy][c0];
                float4 xbv = *(const float4*)&xs[ic][trow + dy][c0 + 4];
                float4 xc = *(const float4*)&xs[ic][trow + dy][c0 + 8];
                float xr[12] = {xa.x, xa.y, xa.z, xa.w,
                                xbv.x, xbv.y, xbv.z, xbv.w,
                                xc.x, xc.y, xc.z, xc.w};
#pragma unroll
                for (int dx = 0; dx < 3; ++dx) {
                    float4 w0 = *(const float4*)&wsh[ic][dy * 3 + dx][toc * 8];
                    float4 w1 = *(const float4*)&wsh[ic][dy * 3 + dx][toc * 8 + 4];
                    float wv[8] = {w0.x, w0.y, w0.z, w0.w, w1.x, w1.y, w1.z, w1.w};
#pragma unroll
                    for (int p = 0; p < 8; ++p)
#pragma unroll
                        for (int o = 0; o < 8; ++o)
                            acc[o][p] = fmaf(wv[o], xr[p + dx], acc[o][p]);
                }
            }
        }
    }

    int y = y0 + trow;
    if (y < H_) {
        float s[8], tt[8];
#pragma unroll
        for (int o = 0; o < 8; ++o) {
            s[o] = sa[oc0 + toc * 8 + o];
            tt[o] = ta[oc0 + toc * 8 + o];
        }
        int px_base = b * (H_ * W_) + y * W_ + x0 + c0;
#pragma unroll
        for (int p = 0; p < 8; ++p) {
            float4 v0, v1;
            v0.x = fmaxf(fmaf(acc[0][p], s[0], tt[0]), 0.f);
            v0.y = fmaxf(fmaf(acc[1][p], s[1], tt[1]), 0.f);
            v0.z = fmaxf(fmaf(acc[2][p], s[2], tt[2]), 0.f);
            v0.w = fmaxf(fmaf(acc[3][p], s[3], tt[3]), 0.f);
            v1.x = fmaxf(fmaf(acc[4][p], s[4], tt[4]), 0.f);
            v1.y = fmaxf(fmaf(acc[5][p], s[5], tt[5]), 0.f);
            v1.z = fmaxf(fmaf(acc[6][p], s[6], tt[6]), 0.f);
            v1.w = fmaxf(fmaf(acc[7][p], s[7], tt[7]), 0.f);
            float* hp = h + (size_t)(px_base + p) * CHID + oc0 + toc * 8;
            *(float4*)hp = v0;
            *(float4*)(hp + 4) = v1;
        }
    }
}

// =====================================================================
// K1b: conv3x3 packed-f32 experiment (v2f accumulate -> v_pk_fma_f32?)
// same math, same staging; only inner loop differs
// =====================================================================
__global__ __launch_bounds__(256) void conv3_pk_kernel(const float* __restrict__ x,
                                                       const float* __restrict__ wt,
                                                       const float* __restrict__ sa,
                                                       const float* __restrict__ ta,
                                                       float* __restrict__ h, int b0)
{
    CONV3_PROLOGUE

    v2f acc2[8][4];   // [oc][px pair]
#pragma unroll
    for (int o = 0; o < 8; ++o)
#pragma unroll
        for (int p = 0; p < 4; ++p) acc2[o][p] = (v2f)(0.f);

    for (int cc = 0; cc < 16; ++cc) {
        CONV3_STAGE(cc)
#pragma unroll
        for (int ic = 0; ic < 8; ++ic) {
#pragma unroll
            for (int dy = 0; dy < 3; ++dy) {
                float4 xa = *(const float4*)&xs[ic][trow + dy][c0];
                float4 xbv = *(const float4*)&xs[ic][trow + dy][c0 + 4];
                float4 xc = *(const float4*)&xs[ic][trow + dy][c0 + 8];
                float xr[10] = {xa.x, xa.y, xa.z, xa.w,
                                xbv.x, xbv.y, xbv.z, xbv.w,
                                xc.x, xc.y};
                v2f pe[5], po[4];
#pragma unroll
                for (int i = 0; i < 5; ++i) { pe[i].x = xr[2 * i]; pe[i].y = xr[2 * i + 1]; }
#pragma unroll
                for (int i = 0; i < 4; ++i) { po[i].x = xr[2 * i + 1]; po[i].y = xr[2 * i + 2]; }
#pragma unroll
                for (int dx = 0; dx < 3; ++dx) {
                    float4 w0 = *(const float4*)&wsh[ic][dy * 3 + dx][toc * 8];
                    float4 w1 = *(const float4*)&wsh[ic][dy * 3 + dx][toc * 8 + 4];
                    float wv[8] = {w0.x, w0.y, w0.z, w0.w, w1.x, w1.y, w1.z, w1.w};
#pragma unroll
                    for (int o = 0; o < 8; ++o) {
                        v2f w2;
                        w2.x = wv[o]; w2.y = wv[o];
#pragma unroll
                        for (int p2 = 0; p2 < 4; ++p2) {
                            v2f xp = (dx == 0) ? pe[p2] : (dx == 1) ? po[p2] : pe[p2 + 1];
                            acc2[o][p2] = w2 * xp + acc2[o][p2];
                        }
                    }
                }
            }
        }
    }

    int y = y0 + trow;
    if (y < H_) {
        float s[8], tt[8];
#pragma unroll
        for (int o = 0; o < 8; ++o) {
            s[o] = sa[oc0 + toc * 8 + o];
            tt[o] = ta[oc0 + toc * 8 + o];
        }
        int px_base = b * (H_ * W_) + y * W_ + x0 + c0;
#pragma unroll
        for (int p = 0; p < 8; ++p) {
            float av[8];
#pragma unroll
            for (int o = 0; o < 8; ++o)
                av[o] = (p & 1) ? acc2[o][p >> 1].y : acc2[o][p >> 1].x;
            float4 v0, v1;
            v0.x = fmaxf(fmaf(av[0], s[0], tt[0]), 0.f);
            v0.y = fmaxf(fmaf(av[1], s[1], tt[1]), 0.f);
            v0.z = fmaxf(fmaf(av[2], s[2], tt[2]), 0.f);
            v0.w = fmaxf(fmaf(av[3], s[3], tt[3]), 0.f);
            v1.x = fmaxf(fmaf(av[4], s[4], tt[4]), 0.f);
            v1.y = fmaxf(fmaf(av[5], s[5], tt[5]), 0.f);
            v1.z = fmaxf(fmaf(av[6], s[6], tt[6]), 0.f);
            v1.w = fmaxf(fmaf(av[7], s[7], tt[7]), 0.f);
            float* hp = h + (size_t)(px_base + p) * CHID + oc0 + toc * 8;
            *(float4*)hp = v0;
            *(float4*)(hp + 4) = v1;
        }
    }
}

// =====================================================================
// K2: conv1x1 (256->65) + BN, LDS-staged coalesced reads
// block = 256 threads = 256 pixels; 8 chunks of 32 channels
// =====================================================================
__global__ __launch_bounds__(256) void conv1_kernel(const float* __restrict__ h,
                                                    const float* __restrict__ wt1,
                                                    const float* __restrict__ tb,
                                                    float* __restrict__ logits,
                                                    float* __restrict__ prob)
{
    __shared__ float hs[256 * 33];
    int p0 = blockIdx.x * 256;
    int t = threadIdx.x;

    float acc[COUT];
#pragma unroll
    for (int oc = 0; oc < COUT; ++oc) acc[oc] = 0.f;

#pragma unroll 1
    for (int kc = 0; kc < 8; ++kc) {
        __syncthreads();
#pragma unroll
        for (int i = 0; i < 8; ++i) {
            int idx = t + i * 256;            // [0,2048)
            int px = idx >> 3, c4 = idx & 7;
            float4 v = *(const float4*)&h[(size_t)(p0 + px) * CHID + kc * 32 + c4 * 4];
            float* d = &hs[px * 33 + c4 * 4];
            d[0] = v.x; d[1] = v.y; d[2] = v.z; d[3] = v.w;
        }
        __syncthreads();

        float hv[32];
#pragma unroll
        for (int k = 0; k < 32; ++k) hv[k] = hs[t * 33 + k];

#pragma unroll
        for (int oc = 0; oc < COUT; ++oc) {
            const float* wr = wt1 + oc * CHID + kc * 32;   // uniform -> s_load
#pragma unroll
            for (int k = 0; k < 32; ++k)
                acc[oc] = fmaf(wr[k], hv[k], acc[oc]);
        }
    }

    int p = p0 + t;
    int b = p / (H_ * W_);
    int yx = p % (H_ * W_);
    int y = yx / W_;
    int xx = yx % W_;

    float v[COUT];
#pragma unroll
    for (int oc = 0; oc < COUT; ++oc)
        v[oc] = acc[oc] + tb[oc];

#pragma unroll
    for (int oc = 0; oc < COUT; ++oc)
        logits[((size_t)(b * COUT + oc)) * (H_ * W_) + yx] = v[oc];

    float* pb = prob + (size_t)b * (HP * WP);
#pragma unroll
    for (int r1 = 0; r1 < 8; ++r1) {
        float4 a0, a1;
        a0.x = v[r1 * 8 + 0]; a0.y = v[r1 * 8 + 1]; a0.z = v[r1 * 8 + 2]; a0.w = v[r1 * 8 + 3];
        a1.x = v[r1 * 8 + 4]; a1.y = v[r1 * 8 + 5]; a1.z = v[r1 * 8 + 6]; a1.w = v[r1 * 8 + 7];
        float* dst = pb + (y * 8 + r1) * WP + xx * 8;
        *(float4*)dst = a0;
        *(float4*)(dst + 4) = a1;
    }
}

// =====================================================================
// K3: 9x9 local-max keep + positive-candidate compaction
// =====================================================================
__global__ __launch_bounds__(256) void nms_kernel(const float* __restrict__ prob,
                                                  float* __restrict__ keep_out,
                                                  float* __restrict__ cand,
                                                  int* __restrict__ cnt)
{
    __shared__ float xs[40][40];
    __shared__ float rmax[40][32];

    int bid = blockIdx.x;
    int tx = bid % 20;
    int ty = (bid / 20) % 15;
    int b = bid / 300;
    const float* pb = prob + (size_t)b * (HP * WP);
    int t = threadIdx.x;

    for (int idx = t; idx < 1600; idx += 256) {
        int c = idx % 40, r = idx / 40;
        int gy = ty * 32 - 4 + r;
        int gx = tx * 32 - 4 + c;
        float v = -INFINITY;
        if (gy >= 0 && gy < HP && gx >= 0 && gx < WP) v = pb[gy * WP + gx];
        xs[r][c] = v;
    }
    __syncthreads();

    for (int idx = t; idx < 1280; idx += 256) {
        int c = idx & 31, r = idx >> 5;
        float m = xs[r][c];
#pragma unroll
        for (int d = 1; d < 9; ++d) m = fmaxf(m, xs[r][c + d]);
        rmax[r][c] = m;
    }
    __syncthreads();

    for (int idx = t; idx < 1024; idx += 256) {
        int c = idx & 31, ro = idx >> 5;
        float m = rmax[ro][c];
#pragma unroll
        for (int d = 1; d < 9; ++d) m = fmaxf(m, rmax[ro + d][c]);
        float v = xs[ro + 4][c + 4];
        float keep = (v == m) ? v : 0.f;
        keep_out[(size_t)b * (HP * WP) + (ty * 32 + ro) * WP + tx * 32 + c] = keep;
        if (keep > 0.f) {
            int i = atomicAdd(&cnt[b], 1);
            if (i < CAND_MAX) cand[b * CAND_MAX + i] = keep;
        }
    }
}

// =====================================================================
// K4: exact kth-largest (k=1000) per batch via 4-pass radix select
// =====================================================================
__global__ __launch_bounds__(256) void select_kernel(const float* __restrict__ cand,
                                                     const int* __restrict__ cnt,
                                                     float* __restrict__ kth)
{
    __shared__ unsigned hist[256];
    __shared__ unsigned sh_prefix, sh_K;

    int b = blockIdx.x;
    int t = threadIdx.x;
    int n = cnt[b];
    if (n > CAND_MAX) n = CAND_MAX;
    if (n < TOPK) {
        if (t == 0) kth[b] = 0.f;
        return;
    }
    if (t == 0) { sh_prefix = 0u; sh_K = TOPK; }
    __syncthreads();
    const float* cb = cand + b * CAND_MAX;

    for (int pass = 3; pass >= 0; --pass) {
        hist[t] = 0u;
        __syncthreads();
        unsigned prefix = sh_prefix;
        unsigned himask = (pass == 3) ? 0u : (0xFFFFFFFFu << ((pass + 1) * 8));
        for (int i = t; i < n; i += 256) {
            unsigned u = __float_as_uint(cb[i]);
            if ((u & himask) == prefix)
                atomicAdd(&hist[(u >> (pass * 8)) & 255], 1u);
        }
        __syncthreads();
        if (t == 0) {
            unsigned K = sh_K, cum = 0;
            int sel = 0;
            for (int v2 = 255; v2 >= 0; --v2) {
                if (cum + hist[v2] >= K) { sel = v2; sh_K = K - cum; break; }
                cum += hist[v2];
            }
            sh_prefix = prefix | ((unsigned)sel << (pass * 8));
        }
        __syncthreads();
    }
    if (t == 0) kth[b] = __uint_as_float(sh_prefix);
}

// =====================================================================
// K5: threshold with kth + binarize
// =====================================================================
__global__ __launch_bounds__(256) void thresh_kernel(const float* __restrict__ keep,
                                                     const float* __restrict__ kth,
                                                     float* __restrict__ prob_nms,
                                                     float* __restrict__ pred)
{
    int i4 = blockIdx.x * 256 + threadIdx.x;
    int b = i4 / (HP * WP / 4);
    float tv = kth[b];
    float4 v = ((const float4*)keep)[i4];
    float4 o;
    o.x = (v.x >= tv) ? v.x : 0.f;
    o.y = (v.y >= tv) ? v.y : 0.f;
    o.z = (v.z >= tv) ? v.z : 0.f;
    o.w = (v.w >= tv) ? v.w : 0.f;
    ((float4*)prob_nms)[i4] = o;
    float4 pr;
    pr.x = (o.x >= DET_THRESH) ? 1.f : 0.f;
    pr.y = (o.y >= DET_THRESH) ? 1.f : 0.f;
    pr.z = (o.z >= DET_THRESH) ? 1.f : 0.f;
    pr.w = (o.w >= DET_THRESH) ? 1.f : 0.f;
    ((float4*)pred)[i4] = pr;
}

// =====================================================================
extern "C" void kernel_launch(void* const* d_in, const int* in_sizes, int n_in,
                              void* d_out, int out_size, void* d_ws, size_t ws_size,
                              hipStream_t stream) {
    const float* x   = (const float*)d_in[0];
    const float* wa  = (const float*)d_in[1];
    const float* ba  = (const float*)d_in[2];
    const float* ga  = (const float*)d_in[3];
    const float* bta = (const float*)d_in[4];
    const float* ma  = (const float*)d_in[5];
    const float* va  = (const float*)d_in[6];
    const float* wb  = (const float*)d_in[7];
    const float* bb  = (const float*)d_in[8];
    const float* gb  = (const float*)d_in[9];
    const float* btb = (const float*)d_in[10];
    const float* mb  = (const float*)d_in[11];
    const float* vb  = (const float*)d_in[12];

    float* out = (float*)d_out;
    float* ws  = (float*)d_ws;

    float* wt   = ws + WT_OFF;
    float* sa   = ws + SA_OFF;
    float* ta   = ws + TA_OFF;
    float* tbv  = ws + TB_OFF;
    float* h    = ws + H_OFF;
    float* cand = ws + CAND_OFF;
    int*   cnt  = (int*)(ws + CNT_OFF);
    float* kth  = ws + KTH_OFF;
    float* wt1  = ws + WT1_OFF;

    hipMemsetAsync((void*)cnt, 0, 32 * sizeof(int), stream);

    {
        int total = WT_N + 256 + COUT + WT1_N;
        prep_kernel<<<(total + 255) / 256, 256, 0, stream>>>(
            wa, ba, ga, bta, ma, va, wb, bb, gb, btb, mb, vb, wt, sa, ta, tbv, wt1);
    }

    // A/B: first 16 images scalar, last 16 images packed-f32
    conv3_kernel<<<16 * 80, 256, 0, stream>>>(x, wt, sa, ta, h, 0);
    conv3_pk_kernel<<<16 * 80, 256, 0, stream>>>(x, wt, sa, ta, h, 16);

    conv1_kernel<<<(B_ * H_ * W_) / 256, 256, 0, stream>>>(
        h, wt1, tbv, out, out + PROB_OFF);

    nms_kernel<<<32 * 15 * 20, 256, 0, stream>>>(
        out + PROB_OFF, out + NMS_OFF, cand, cnt);

    select_kernel<<<B_, 256, 0, stream>>>(cand, cnt, kth);

    thresh_kernel<<<(PROB_N / 4) / 256, 256, 0, stream>>>(
        out + NMS_OFF, kth, out + NMS_OFF, out + PRED_OFF);
}

// Round 3
// 1919.423 us; speedup vs baseline: 1.6930x; 1.6930x over previous
//
#include <hip/hip_runtime.h>
#include <math.h>

typedef float v2f __attribute__((ext_vector_type(2)));

// ---------------- problem constants ----------------
#define B_    32
#define CIN   128
#define CHID  256
#define H_    60
#define W_    80
#define COUT  65
#define HP    480
#define WP    640
#define TOPK  1000
#define CAND_MAX 8192
#define DET_THRESH 0.015f

// ---------------- output layout (floats) ----------------
#define LOGITS_N (B_*COUT*H_*W_)        // 9,984,000
#define PROB_N   (B_*HP*WP)             // 9,830,400
#define PROB_OFF (LOGITS_N)
#define NMS_OFF  (PROB_OFF + PROB_N)
#define PRED_OFF (NMS_OFF + PROB_N)

// ---------------- workspace layout (float offsets) ----------------
#define WT_N   (CHID*CIN*9)             // 294,912
#define WT_OFF 0
#define SA_OFF (WT_OFF + WT_N)
#define TA_OFF (SA_OFF + 256)
#define SB_OFF (TA_OFF + 256)
#define TB_OFF (SB_OFF + 128)
#define H_OFF  (TB_OFF + 128)
#define H_N    (B_*H_*W_*CHID)          // 39,321,600
#define CAND_OFF (H_OFF + H_N)
// cnt: 32 batches x 32-int stride (128B) to kill cross-XCD line ping-pong
#define CNT_OFF  (CAND_OFF + B_*CAND_MAX)
#define CNT_N    (32*32)
#define KTH_OFF  (CNT_OFF + CNT_N)

// =====================================================================
// K0: weight transpose (conv3) + BN folding (sa/ta for conv3, sb/tb for conv1)
// =====================================================================
__global__ void prep_kernel(const float* __restrict__ wa,
                            const float* __restrict__ ba, const float* __restrict__ ga,
                            const float* __restrict__ bta, const float* __restrict__ ma,
                            const float* __restrict__ va,
                            const float* __restrict__ bb, const float* __restrict__ gb,
                            const float* __restrict__ btb, const float* __restrict__ mb,
                            const float* __restrict__ vb,
                            float* __restrict__ wt,
                            float* __restrict__ sa, float* __restrict__ ta,
                            float* __restrict__ sb, float* __restrict__ tb)
{
    int gid = blockIdx.x * 256 + threadIdx.x;
    if (gid < WT_N) {
        int oc = gid & 255;
        int rest = gid >> 8;          // [0,1152)
        int s = rest % 3;
        int r = (rest / 3) % 3;
        int ic = rest / 9;
        wt[gid] = wa[((oc * CIN + ic) * 3 + r) * 3 + s];
    } else if (gid < WT_N + 256) {
        int oc = gid - WT_N;
        float inv = ga[oc] / sqrtf(va[oc] + 1e-5f);
        sa[oc] = inv;
        ta[oc] = (ba[oc] - ma[oc]) * inv + bta[oc];
    } else if (gid < WT_N + 256 + COUT) {
        int oc = gid - (WT_N + 256);
        float inv = gb[oc] / sqrtf(vb[oc] + 1e-5f);
        sb[oc] = inv;
        tb[oc] = (bb[oc] - mb[oc]) * inv + btb[oc];
    }
}

// =====================================================================
// conv3 shared staging macro (identical for both variants)
// =====================================================================
#define CONV3_PROLOGUE                                                          \
    __shared__ float xs[8][18][20];                                             \
    __shared__ float wsh[8][9][64];                                             \
    int bid = blockIdx.x;                                                       \
    int ct = bid % 5;                                                           \
    int rt = (bid / 5) & 3;                                                     \
    int ot = (bid / 20) & 3;                                                    \
    int b  = b0 + bid / 80;                                                     \
    int x0 = ct * 16, y0 = rt * 16, oc0 = ot * 64;                              \
    int t = threadIdx.x;                                                        \
    int toc = t & 7;                                                            \
    int g = t >> 3;                                                             \
    int trow = g & 15;                                                          \
    int c0 = (g >> 4) * 8;                                                      \
    const float* xb = x + (size_t)b * CIN * H_ * W_;

#define CONV3_STAGE(cc)                                                         \
    {                                                                           \
        int ic0 = (cc) * 8;                                                     \
        __syncthreads();                                                        \
        for (int idx = t; idx < 8 * 18 * 18; idx += 256) {                      \
            int c = idx % 18;                                                   \
            int rr = (idx / 18) % 18;                                           \
            int ic = idx / 324;                                                 \
            int gy = y0 - 1 + rr;                                               \
            int gx = x0 - 1 + c;                                                \
            float v = 0.f;                                                      \
            if (gy >= 0 && gy < H_ && gx >= 0 && gx < W_)                       \
                v = xb[(ic0 + ic) * (H_ * W_) + gy * W_ + gx];                  \
            xs[ic][rr][c] = v;                                                  \
        }                                                                       \
        for (int idx = t; idx < 8 * 9 * 64; idx += 256) {                       \
            int ol = idx & 63;                                                  \
            int q = idx >> 6;                                                   \
            int tap = q % 9;                                                    \
            int ic = q / 9;                                                     \
            wsh[ic][tap][ol] = wt[((ic0 + ic) * 9 + tap) * 256 + oc0 + ol];     \
        }                                                                       \
        __syncthreads();                                                        \
    }

// =====================================================================
// K1a: conv3x3 scalar f32
// =====================================================================
__global__ __launch_bounds__(256) void conv3_kernel(const float* __restrict__ x,
                                                    const float* __restrict__ wt,
                                                    const float* __restrict__ sa,
                                                    const float* __restrict__ ta,
                                                    float* __restrict__ h, int b0)
{
    CONV3_PROLOGUE

    float acc[8][8];
#pragma unroll
    for (int o = 0; o < 8; ++o)
#pragma unroll
        for (int p = 0; p < 8; ++p) acc[o][p] = 0.f;

    for (int cc = 0; cc < 16; ++cc) {
        CONV3_STAGE(cc)
#pragma unroll
        for (int ic = 0; ic < 8; ++ic) {
#pragma unroll
            for (int dy = 0; dy < 3; ++dy) {
                float4 xa = *(const float4*)&xs[ic][trow + dy][c0];
                float4 xbv = *(const float4*)&xs[ic][trow + dy][c0 + 4];
                float4 xc = *(const float4*)&xs[ic][trow + dy][c0 + 8];
                float xr[12] = {xa.x, xa.y, xa.z, xa.w,
                                xbv.x, xbv.y, xbv.z, xbv.w,
                                xc.x, xc.y, xc.z, xc.w};
#pragma unroll
                for (int dx = 0; dx < 3; ++dx) {
                    float4 w0 = *(const float4*)&wsh[ic][dy * 3 + dx][toc * 8];
                    float4 w1 = *(const float4*)&wsh[ic][dy * 3 + dx][toc * 8 + 4];
                    float wv[8] = {w0.x, w0.y, w0.z, w0.w, w1.x, w1.y, w1.z, w1.w};
#pragma unroll
                    for (int p = 0; p < 8; ++p)
#pragma unroll
                        for (int o = 0; o < 8; ++o)
                            acc[o][p] = fmaf(wv[o], xr[p + dx], acc[o][p]);
                }
            }
        }
    }

    int y = y0 + trow;
    if (y < H_) {
        float s[8], tt[8];
#pragma unroll
        for (int o = 0; o < 8; ++o) {
            s[o] = sa[oc0 + toc * 8 + o];
            tt[o] = ta[oc0 + toc * 8 + o];
        }
        int px_base = b * (H_ * W_) + y * W_ + x0 + c0;
#pragma unroll
        for (int p = 0; p < 8; ++p) {
            float4 v0, v1;
            v0.x = fmaxf(fmaf(acc[0][p], s[0], tt[0]), 0.f);
            v0.y = fmaxf(fmaf(acc[1][p], s[1], tt[1]), 0.f);
            v0.z = fmaxf(fmaf(acc[2][p], s[2], tt[2]), 0.f);
            v0.w = fmaxf(fmaf(acc[3][p], s[3], tt[3]), 0.f);
            v1.x = fmaxf(fmaf(acc[4][p], s[4], tt[4]), 0.f);
            v1.y = fmaxf(fmaf(acc[5][p], s[5], tt[5]), 0.f);
            v1.z = fmaxf(fmaf(acc[6][p], s[6], tt[6]), 0.f);
            v1.w = fmaxf(fmaf(acc[7][p], s[7], tt[7]), 0.f);
            float* hp = h + (size_t)(px_base + p) * CHID + oc0 + toc * 8;
            *(float4*)hp = v0;
            *(float4*)(hp + 4) = v1;
        }
    }
}

// =====================================================================
// K1b: conv3x3 packed-f32 experiment (v2f accumulate -> v_pk_fma_f32?)
// =====================================================================
__global__ __launch_bounds__(256) void conv3_pk_kernel(const float* __restrict__ x,
                                                       const float* __restrict__ wt,
                                                       const float* __restrict__ sa,
                                                       const float* __restrict__ ta,
                                                       float* __restrict__ h, int b0)
{
    CONV3_PROLOGUE

    v2f acc2[8][4];   // [oc][px pair]
#pragma unroll
    for (int o = 0; o < 8; ++o)
#pragma unroll
        for (int p = 0; p < 4; ++p) acc2[o][p] = (v2f)(0.f);

    for (int cc = 0; cc < 16; ++cc) {
        CONV3_STAGE(cc)
#pragma unroll
        for (int ic = 0; ic < 8; ++ic) {
#pragma unroll
            for (int dy = 0; dy < 3; ++dy) {
                float4 xa = *(const float4*)&xs[ic][trow + dy][c0];
                float4 xbv = *(const float4*)&xs[ic][trow + dy][c0 + 4];
                float4 xc = *(const float4*)&xs[ic][trow + dy][c0 + 8];
                float xr[10] = {xa.x, xa.y, xa.z, xa.w,
                                xbv.x, xbv.y, xbv.z, xbv.w,
                                xc.x, xc.y};
                v2f pe[5], po[4];
#pragma unroll
                for (int i = 0; i < 5; ++i) { pe[i].x = xr[2 * i]; pe[i].y = xr[2 * i + 1]; }
#pragma unroll
                for (int i = 0; i < 4; ++i) { po[i].x = xr[2 * i + 1]; po[i].y = xr[2 * i + 2]; }
#pragma unroll
                for (int dx = 0; dx < 3; ++dx) {
                    float4 w0 = *(const float4*)&wsh[ic][dy * 3 + dx][toc * 8];
                    float4 w1 = *(const float4*)&wsh[ic][dy * 3 + dx][toc * 8 + 4];
                    float wv[8] = {w0.x, w0.y, w0.z, w0.w, w1.x, w1.y, w1.z, w1.w};
#pragma unroll
                    for (int o = 0; o < 8; ++o) {
                        v2f w2;
                        w2.x = wv[o]; w2.y = wv[o];
#pragma unroll
                        for (int p2 = 0; p2 < 4; ++p2) {
                            v2f xp = (dx == 0) ? pe[p2] : (dx == 1) ? po[p2] : pe[p2 + 1];
                            acc2[o][p2] = w2 * xp + acc2[o][p2];
                        }
                    }
                }
            }
        }
    }

    int y = y0 + trow;
    if (y < H_) {
        float s[8], tt[8];
#pragma unroll
        for (int o = 0; o < 8; ++o) {
            s[o] = sa[oc0 + toc * 8 + o];
            tt[o] = ta[oc0 + toc * 8 + o];
        }
        int px_base = b * (H_ * W_) + y * W_ + x0 + c0;
#pragma unroll
        for (int p = 0; p < 8; ++p) {
            float av[8];
#pragma unroll
            for (int o = 0; o < 8; ++o)
                av[o] = (p & 1) ? acc2[o][p >> 1].y : acc2[o][p >> 1].x;
            float4 v0, v1;
            v0.x = fmaxf(fmaf(av[0], s[0], tt[0]), 0.f);
            v0.y = fmaxf(fmaf(av[1], s[1], tt[1]), 0.f);
            v0.z = fmaxf(fmaf(av[2], s[2], tt[2]), 0.f);
            v0.w = fmaxf(fmaf(av[3], s[3], tt[3]), 0.f);
            v1.x = fmaxf(fmaf(av[4], s[4], tt[4]), 0.f);
            v1.y = fmaxf(fmaf(av[5], s[5], tt[5]), 0.f);
            v1.z = fmaxf(fmaf(av[6], s[6], tt[6]), 0.f);
            v1.w = fmaxf(fmaf(av[7], s[7], tt[7]), 0.f);
            float* hp = h + (size_t)(px_base + p) * CHID + oc0 + toc * 8;
            *(float4*)hp = v0;
            *(float4*)(hp + 4) = v1;
        }
    }
}

// =====================================================================
// K2: conv1x1 (256->65) + BN  (round-1 form: per-thread pixel, bcast weights)
// =====================================================================
__global__ __launch_bounds__(256) void conv1_kernel(const float* __restrict__ h,
                                                    const float* __restrict__ wb,
                                                    const float* __restrict__ sb,
                                                    const float* __restrict__ tb,
                                                    float* __restrict__ logits,
                                                    float* __restrict__ prob)
{
    int p = blockIdx.x * 256 + threadIdx.x;     // [0, 153600)
    int b = p / (H_ * W_);
    int yx = p % (H_ * W_);
    int y = yx / W_;
    int xx = yx % W_;
    const float* hp = h + (size_t)p * CHID;

    float acc[COUT];
#pragma unroll
    for (int oc = 0; oc < COUT; ++oc) acc[oc] = 0.f;

#pragma unroll 2
    for (int kc = 0; kc < 32; ++kc) {
        float4 h0 = *(const float4*)(hp + kc * 8);
        float4 h1 = *(const float4*)(hp + kc * 8 + 4);
        float hv[8] = {h0.x, h0.y, h0.z, h0.w, h1.x, h1.y, h1.z, h1.w};
#pragma unroll
        for (int oc = 0; oc < COUT; ++oc) {
            const float* wr = wb + oc * CHID + kc * 8;
            float a = acc[oc];
            a = fmaf(wr[0], hv[0], a);
            a = fmaf(wr[1], hv[1], a);
            a = fmaf(wr[2], hv[2], a);
            a = fmaf(wr[3], hv[3], a);
            a = fmaf(wr[4], hv[4], a);
            a = fmaf(wr[5], hv[5], a);
            a = fmaf(wr[6], hv[6], a);
            a = fmaf(wr[7], hv[7], a);
            acc[oc] = a;
        }
    }

    float v[COUT];
#pragma unroll
    for (int oc = 0; oc < COUT; ++oc)
        v[oc] = fmaf(acc[oc], sb[oc], tb[oc]);

#pragma unroll
    for (int oc = 0; oc < COUT; ++oc)
        logits[((size_t)(b * COUT + oc)) * (H_ * W_) + yx] = v[oc];

    float* pb = prob + (size_t)b * (HP * WP);
#pragma unroll
    for (int r1 = 0; r1 < 8; ++r1) {
        float4 a0, a1;
        a0.x = v[r1 * 8 + 0]; a0.y = v[r1 * 8 + 1]; a0.z = v[r1 * 8 + 2]; a0.w = v[r1 * 8 + 3];
        a1.x = v[r1 * 8 + 4]; a1.y = v[r1 * 8 + 5]; a1.z = v[r1 * 8 + 6]; a1.w = v[r1 * 8 + 7];
        float* dst = pb + (y * 8 + r1) * WP + xx * 8;
        *(float4*)dst = a0;
        *(float4*)(dst + 4) = a1;
    }
}

// =====================================================================
// K3: 9x9 local-max keep + candidate compaction
// Per-block LDS compaction -> ONE global atomicAdd per block (padded cnt).
// =====================================================================
__global__ __launch_bounds__(256) void nms_kernel(const float* __restrict__ prob,
                                                  float* __restrict__ keep_out,
                                                  float* __restrict__ cand,
                                                  int* __restrict__ cnt)
{
    __shared__ float xs[40][40];
    __shared__ float rmax[40][32];
    __shared__ float clist[1024];
    __shared__ int csh;
    __shared__ int gbase;

    int bid = blockIdx.x;
    int tx = bid % 20;
    int ty = (bid / 20) % 15;
    int b = bid / 300;
    const float* pb = prob + (size_t)b * (HP * WP);
    int t = threadIdx.x;

    if (t == 0) csh = 0;

    for (int idx = t; idx < 1600; idx += 256) {
        int c = idx % 40, r = idx / 40;
        int gy = ty * 32 - 4 + r;
        int gx = tx * 32 - 4 + c;
        float v = -INFINITY;
        if (gy >= 0 && gy < HP && gx >= 0 && gx < WP) v = pb[gy * WP + gx];
        xs[r][c] = v;
    }
    __syncthreads();

    for (int idx = t; idx < 1280; idx += 256) {
        int c = idx & 31, r = idx >> 5;
        float m = xs[r][c];
#pragma unroll
        for (int d = 1; d < 9; ++d) m = fmaxf(m, xs[r][c + d]);
        rmax[r][c] = m;
    }
    __syncthreads();

    for (int idx = t; idx < 1024; idx += 256) {
        int c = idx & 31, ro = idx >> 5;
        float m = rmax[ro][c];
#pragma unroll
        for (int d = 1; d < 9; ++d) m = fmaxf(m, rmax[ro + d][c]);
        float v = xs[ro + 4][c + 4];
        float keep = (v == m) ? v : 0.f;
        keep_out[(size_t)b * (HP * WP) + (ty * 32 + ro) * WP + tx * 32 + c] = keep;
        if (keep > 0.f) {
            int i = atomicAdd(&csh, 1);     // LDS atomic: cheap
            clist[i] = keep;
        }
    }
    __syncthreads();

    int m = csh;
    if (m > 0) {
        if (t == 0) gbase = atomicAdd(&cnt[b * 32], m);  // one global atomic/block
        __syncthreads();
        int gb = gbase;
        for (int i = t; i < m; i += 256) {
            int dst = gb + i;
            if (dst < CAND_MAX) cand[b * CAND_MAX + dst] = clist[i];
        }
    }
}

// =====================================================================
// K4: exact kth-largest (k=1000) per batch via 4-pass radix select
// =====================================================================
__global__ __launch_bounds__(256) void select_kernel(const float* __restrict__ cand,
                                                     const int* __restrict__ cnt,
                                                     float* __restrict__ kth)
{
    __shared__ unsigned hist[256];
    __shared__ unsigned sh_prefix, sh_K;

    int b = blockIdx.x;
    int t = threadIdx.x;
    int n = cnt[b * 32];
    if (n > CAND_MAX) n = CAND_MAX;
    if (n < TOPK) {
        if (t == 0) kth[b] = 0.f;
        return;
    }
    if (t == 0) { sh_prefix = 0u; sh_K = TOPK; }
    __syncthreads();
    const float* cb = cand + b * CAND_MAX;

    for (int pass = 3; pass >= 0; --pass) {
        hist[t] = 0u;
        __syncthreads();
        unsigned prefix = sh_prefix;
        unsigned himask = (pass == 3) ? 0u : (0xFFFFFFFFu << ((pass + 1) * 8));
        for (int i = t; i < n; i += 256) {
            unsigned u = __float_as_uint(cb[i]);
            if ((u & himask) == prefix)
                atomicAdd(&hist[(u >> (pass * 8)) & 255], 1u);
        }
        __syncthreads();
        if (t == 0) {
            unsigned K = sh_K, cum = 0;
            int sel = 0;
            for (int v2 = 255; v2 >= 0; --v2) {
                if (cum + hist[v2] >= K) { sel = v2; sh_K = K - cum; break; }
                cum += hist[v2];
            }
            sh_prefix = prefix | ((unsigned)sel << (pass * 8));
        }
        __syncthreads();
    }
    if (t == 0) kth[b] = __uint_as_float(sh_prefix);
}

// =====================================================================
// K5: threshold with kth + binarize
// =====================================================================
__global__ __launch_bounds__(256) void thresh_kernel(const float* __restrict__ keep,
                                                     const float* __restrict__ kth,
                                                     float* __restrict__ prob_nms,
                                                     float* __restrict__ pred)
{
    int i4 = blockIdx.x * 256 + threadIdx.x;
    int b = i4 / (HP * WP / 4);
    float tv = kth[b];
    float4 v = ((const float4*)keep)[i4];
    float4 o;
    o.x = (v.x >= tv) ? v.x : 0.f;
    o.y = (v.y >= tv) ? v.y : 0.f;
    o.z = (v.z >= tv) ? v.z : 0.f;
    o.w = (v.w >= tv) ? v.w : 0.f;
    ((float4*)prob_nms)[i4] = o;
    float4 pr;
    pr.x = (o.x >= DET_THRESH) ? 1.f : 0.f;
    pr.y = (o.y >= DET_THRESH) ? 1.f : 0.f;
    pr.z = (o.z >= DET_THRESH) ? 1.f : 0.f;
    pr.w = (o.w >= DET_THRESH) ? 1.f : 0.f;
    ((float4*)pred)[i4] = pr;
}

// =====================================================================
extern "C" void kernel_launch(void* const* d_in, const int* in_sizes, int n_in,
                              void* d_out, int out_size, void* d_ws, size_t ws_size,
                              hipStream_t stream) {
    const float* x   = (const float*)d_in[0];
    const float* wa  = (const float*)d_in[1];
    const float* ba  = (const float*)d_in[2];
    const float* ga  = (const float*)d_in[3];
    const float* bta = (const float*)d_in[4];
    const float* ma  = (const float*)d_in[5];
    const float* va  = (const float*)d_in[6];
    const float* wb  = (const float*)d_in[7];
    const float* bb  = (const float*)d_in[8];
    const float* gb  = (const float*)d_in[9];
    const float* btb = (const float*)d_in[10];
    const float* mb  = (const float*)d_in[11];
    const float* vb  = (const float*)d_in[12];

    float* out = (float*)d_out;
    float* ws  = (float*)d_ws;

    float* wt   = ws + WT_OFF;
    float* sa   = ws + SA_OFF;
    float* ta   = ws + TA_OFF;
    float* sbv  = ws + SB_OFF;
    float* tbv  = ws + TB_OFF;
    float* h    = ws + H_OFF;
    float* cand = ws + CAND_OFF;
    int*   cnt  = (int*)(ws + CNT_OFF);
    float* kth  = ws + KTH_OFF;

    hipMemsetAsync((void*)cnt, 0, CNT_N * sizeof(int), stream);

    {
        int total = WT_N + 256 + COUT;
        prep_kernel<<<(total + 255) / 256, 256, 0, stream>>>(
            wa, ba, ga, bta, ma, va, bb, gb, btb, mb, vb, wt, sa, ta, sbv, tbv);
    }

    // A/B: first 16 images scalar, last 16 images packed-f32
    conv3_kernel<<<16 * 80, 256, 0, stream>>>(x, wt, sa, ta, h, 0);
    conv3_pk_kernel<<<16 * 80, 256, 0, stream>>>(x, wt, sa, ta, h, 16);

    conv1_kernel<<<(B_ * H_ * W_) / 256, 256, 0, stream>>>(
        h, wb, sbv, tbv, out, out + PROB_OFF);

    nms_kernel<<<32 * 15 * 20, 256, 0, stream>>>(
        out + PROB_OFF, out + NMS_OFF, cand, cnt);

    select_kernel<<<B_, 256, 0, stream>>>(cand, cnt, kth);

    thresh_kernel<<<(PROB_N / 4) / 256, 256, 0, stream>>>(
        out + NMS_OFF, kth, out + NMS_OFF, out + PRED_OFF);
}